// Round 4
// baseline (211.152 us; speedup 1.0000x reference)
//
#include <hip/hip_runtime.h>
#include <hip/hip_bf16.h>
#include <hip/hip_fp16.h>
#include <math.h>

// ---- types ----
using f32x4  = __attribute__((ext_vector_type(4))) float;
using half8  = __attribute__((ext_vector_type(8))) _Float16;
using uint4v = __attribute__((ext_vector_type(4))) unsigned int;

__device__ __forceinline__ unsigned short f32_to_f16u(float f) {
  return __half_as_ushort(__float2half(f));
}
__device__ __forceinline__ f32x4 mfma16(half8 a, half8 b, f32x4 c) {
  return __builtin_amdgcn_mfma_f32_16x16x32_f16(a, b, c, 0, 0, 0);
}
__device__ __forceinline__ float gelu_exact(float x) {
  return 0.5f * x * (1.0f + erff(x * 0.70710678118654752440f));
}
__device__ __forceinline__ half8 cvt8(f32x4 lo, f32x4 hi) {
  half8 r;
  r[0] = (_Float16)lo[0]; r[1] = (_Float16)lo[1];
  r[2] = (_Float16)lo[2]; r[3] = (_Float16)lo[3];
  r[4] = (_Float16)hi[0]; r[5] = (_Float16)hi[1];
  r[6] = (_Float16)hi[2]; r[7] = (_Float16)hi[3];
  return r;
}

// ---- problem constants ----
// B=32768, D=768, H1=256, E=128, N=500(pad 512), K_imp=902(pad 960)

// ---------------------------------------------------------------------------
// prep: weight transposes -> f16 [N][K] row-major; centroid pad + norms;
// packed f16 tail[B][8] = {reward, ts, emo0..3, 0, 0}  (k 896..903)
// ---------------------------------------------------------------------------
__global__ __launch_bounds__(256) void k_prep(
    const float* __restrict__ enc_w1, const float* __restrict__ enc_w2,
    const float* __restrict__ imp_w1, const float* __restrict__ cent,
    const float* __restrict__ reward, const float* __restrict__ tsp,
    const float* __restrict__ emo,
    unsigned short* __restrict__ W1T, unsigned short* __restrict__ W2T,
    unsigned short* __restrict__ impW1T, unsigned short* __restrict__ centC,
    float* __restrict__ c_n, unsigned short* __restrict__ tail) {
  int idx = blockIdx.x * 256 + threadIdx.x;
  if (idx < 256 * 768) {               // W1T [256][768]
    int n = idx / 768, k = idx - n * 768;
    W1T[idx] = f32_to_f16u(enc_w1[k * 256 + n]);
  }
  if (idx < 128 * 256) {               // W2T [128][256]
    int n = idx >> 8, k = idx & 255;
    W2T[idx] = f32_to_f16u(enc_w2[k * 128 + n]);
  }
  if (idx < 64 * 960) {                // impW1T [64][960], k>=902 zero
    int n = idx / 960, k = idx - n * 960;
    impW1T[idx] = (k < 902) ? f32_to_f16u(imp_w1[k * 64 + n]) : (unsigned short)0;
  }
  if (idx < 512 * 128) {               // centC [512][128], rows>=500 zero
    int n = idx >> 7, k = idx & 127;
    centC[idx] = (n < 500) ? f32_to_f16u(cent[n * 128 + k]) : (unsigned short)0;
  }
  if (idx < 512) {                     // centroid norms (of f16-rounded values)
    float s = 0.f;
    if (idx < 500) {
      const f32x4* p = (const f32x4*)(cent + idx * 128);
#pragma unroll 8
      for (int j = 0; j < 32; ++j) {
        f32x4 v = p[j];
#pragma unroll
        for (int e = 0; e < 4; ++e) {
          float q = (float)(_Float16)v[e];
          s += q * q;
        }
      }
    }
    c_n[idx] = sqrtf(s);
  }
  if (idx < 32768) {                   // tail pack
    f32x4 e4 = *(const f32x4*)(emo + (size_t)idx * 4);
    unsigned short* tp = tail + (size_t)idx * 8;
    tp[0] = f32_to_f16u(reward[idx]);
    tp[1] = f32_to_f16u(tsp[idx]);
    tp[2] = f32_to_f16u(e4[0]); tp[3] = f32_to_f16u(e4[1]);
    tp[4] = f32_to_f16u(e4[2]); tp[5] = f32_to_f16u(e4[3]);
    tp[6] = 0; tp[7] = 0;
  }
}

// ---------------------------------------------------------------------------
// mega: the whole op for 64 rows per block. 4 waves; wave w owns enc cols
// [w*64, w*64+64) and imp hidden cols [w*16, w*16+16).
// Main loop: NO LDS, NO barriers — A/B fragments loaded directly from
// global (A: cue f32->f16 cvt in regs; B: f16 weights, L2-resident).
// Epilogue: h1 tile -> LDS (swizzled) -> enc2 GEMM -> enc tile -> LDS ->
// cosine sims + streaming top-5; imp head via shfl + LDS partials.
// ---------------------------------------------------------------------------
__global__ __launch_bounds__(256) void k_mega(
    const float* __restrict__ cue, const float* __restrict__ internal,
    const float* __restrict__ emo,
    const unsigned short* __restrict__ W1T, const unsigned short* __restrict__ W2T,
    const unsigned short* __restrict__ impW1T, const unsigned short* __restrict__ centC,
    const unsigned short* __restrict__ tail, const float* __restrict__ c_n,
    const float* __restrict__ b1, const float* __restrict__ b2,
    const float* __restrict__ ib1, const float* __restrict__ iw2,
    const float* __restrict__ ib2, float* __restrict__ out) {
  __shared__ unsigned char sm[50688];
  // [0,32768)     h1 tile  [64 rows][256 cols] f16, swizzle ^((row&7)<<4)
  // [32768,49152) enc tile [64 rows][128 cols] f16, swizzle ^((row&7)<<4)
  // [49152,50176) imp partials float [64][4]
  // [50176,50432) row norms float [64]
  unsigned short* sm16 = (unsigned short*)sm;
  float* s_p  = (float*)(sm + 49152);
  float* s_en = (float*)(sm + 50176);

  const int t = threadIdx.x;
  const int lane = t & 63, w = t >> 6;
  const int g = lane >> 4, c = lane & 15;
  const int row0 = blockIdx.x * 64;

  // ---- fragment base pointers (A rows: mf*16 + c; k-chunk: g*8) ----
  const float* aC = cue + (size_t)(row0 + c) * 768 + g * 8;          // + mf*12288, + s*32
  const float* aI = internal + (size_t)(row0 + c) * 128 + g * 8;     // + mf*2048,  + s2*32
  const unsigned short* b1p0 = W1T + (size_t)(w * 64 + c) * 768 + g * 8;   // + nf*12288, + s*32
  const unsigned short* b2p  = impW1T + (size_t)(w * 16 + c) * 960 + g * 8; // + s*32

  f32x4 acc1[4][4];   // enc1 pre-act: rows mf*16+g*4+rr, cols w*64+nf*16+c
  f32x4 acc2[4];      // imp hidden:   rows mf*16+g*4+rr, col  w*16+c
#pragma unroll
  for (int i = 0; i < 4; ++i) {
    acc2[i] = f32x4{0.f, 0.f, 0.f, 0.f};
#pragma unroll
    for (int j = 0; j < 4; ++j) acc1[i][j] = f32x4{0.f, 0.f, 0.f, 0.f};
  }

  // ---- main stream: K 0..767 (cue) ----
#pragma unroll 4
  for (int s = 0; s < 24; ++s) {
    half8 af[4];
#pragma unroll
    for (int mf = 0; mf < 4; ++mf) {
      const float* p = aC + mf * 12288 + s * 32;
      af[mf] = cvt8(*(const f32x4*)p, *(const f32x4*)(p + 4));
    }
    {
      half8 b2f = *(const half8*)(b2p + s * 32);
#pragma unroll
      for (int mf = 0; mf < 4; ++mf) acc2[mf] = mfma16(af[mf], b2f, acc2[mf]);
    }
#pragma unroll
    for (int nf = 0; nf < 4; ++nf) {
      half8 bf = *(const half8*)(b1p0 + nf * 12288 + s * 32);
#pragma unroll
      for (int mf = 0; mf < 4; ++mf) acc1[mf][nf] = mfma16(af[mf], bf, acc1[mf][nf]);
    }
  }
  // ---- K 768..895 (internal), imp only ----
#pragma unroll
  for (int s2 = 0; s2 < 4; ++s2) {
    half8 af[4];
#pragma unroll
    for (int mf = 0; mf < 4; ++mf) {
      const float* p = aI + mf * 2048 + s2 * 32;
      af[mf] = cvt8(*(const f32x4*)p, *(const f32x4*)(p + 4));
    }
    half8 b2f = *(const half8*)(b2p + (24 + s2) * 32);
#pragma unroll
    for (int mf = 0; mf < 4; ++mf) acc2[mf] = mfma16(af[mf], b2f, acc2[mf]);
  }
  // ---- K 896..927 (tail: rw|ts|emo|0), imp only ----
  {
    half8 zero = half8{};
    half8 b2f = *(const half8*)(b2p + 28 * 32);
#pragma unroll
    for (int mf = 0; mf < 4; ++mf) {
      half8 af = (g == 0) ? *(const half8*)(tail + (size_t)(row0 + mf * 16 + c) * 8) : zero;
      acc2[mf] = mfma16(af, b2f, acc2[mf]);
    }
  }

  // ---- E1: bias + gelu -> h1 tile in LDS (f16, swizzled) ----
  float bias1[4];
#pragma unroll
  for (int nf = 0; nf < 4; ++nf) bias1[nf] = b1[w * 64 + nf * 16 + c];
#pragma unroll
  for (int mf = 0; mf < 4; ++mf)
#pragma unroll
    for (int nf = 0; nf < 4; ++nf)
#pragma unroll
      for (int rr = 0; rr < 4; ++rr) {
        int row = mf * 16 + g * 4 + rr;
        int col = w * 64 + nf * 16 + c;
        float x = gelu_exact(acc1[mf][nf][rr] + bias1[nf]);
        int byte = (row * 512 + col * 2) ^ ((row & 7) << 4);
        sm16[byte >> 1] = f32_to_f16u(x);
      }
  __syncthreads();

  // ---- E2: enc2 GEMM from LDS h1 tile; B = W2T (L2) ----
  f32x4 acc3[4][2];
#pragma unroll
  for (int i = 0; i < 4; ++i)
#pragma unroll
    for (int j = 0; j < 2; ++j) acc3[i][j] = f32x4{0.f, 0.f, 0.f, 0.f};
#pragma unroll
  for (int ks = 0; ks < 8; ++ks) {
    half8 a2[4];
#pragma unroll
    for (int mf = 0; mf < 4; ++mf) {
      int row = mf * 16 + c;
      int byte = (row * 512 + ks * 64 + g * 16) ^ ((row & 7) << 4);
      a2[mf] = *(const half8*)(sm + byte);
    }
#pragma unroll
    for (int nf2 = 0; nf2 < 2; ++nf2) {
      half8 bf = *(const half8*)(W2T + (size_t)(w * 32 + nf2 * 16 + c) * 256 + ks * 32 + g * 8);
#pragma unroll
      for (int mf = 0; mf < 4; ++mf) acc3[mf][nf2] = mfma16(a2[mf], bf, acc3[mf][nf2]);
    }
  }
  // enc tile -> LDS (f16, swizzled), region [32768, 49152)
  float bias2v[2];
#pragma unroll
  for (int nf2 = 0; nf2 < 2; ++nf2) bias2v[nf2] = b2[w * 32 + nf2 * 16 + c];
#pragma unroll
  for (int mf = 0; mf < 4; ++mf)
#pragma unroll
    for (int nf2 = 0; nf2 < 2; ++nf2)
#pragma unroll
      for (int rr = 0; rr < 4; ++rr) {
        int row = mf * 16 + g * 4 + rr;
        int col = w * 32 + nf2 * 16 + c;
        float x = acc3[mf][nf2][rr] + bias2v[nf2];
        int byte = (row * 256 + col * 2) ^ ((row & 7) << 4);
        sm16[(32768 + byte) >> 1] = f32_to_f16u(x);
      }

  // ---- E4a: imp head partials: gelu * w2, reduce over 16 hidden (c) ----
  {
    float b1v = ib1[w * 16 + c];
    float w2v = iw2[w * 16 + c];
#pragma unroll
    for (int mf = 0; mf < 4; ++mf)
#pragma unroll
      for (int rr = 0; rr < 4; ++rr) {
        float v = gelu_exact(acc2[mf][rr] + b1v) * w2v;
        v += __shfl_xor(v, 1);
        v += __shfl_xor(v, 2);
        v += __shfl_xor(v, 4);
        v += __shfl_xor(v, 8);
        if (c == 0) s_p[(mf * 16 + g * 4 + rr) * 4 + w] = v;
      }
  }
  __syncthreads();

  // ---- E4b: imp final (64 threads) ----
  if (t < 64) {
    float ssum = s_p[t * 4 + 0] + s_p[t * 4 + 1] + s_p[t * 4 + 2] + s_p[t * 4 + 3];
    int rowA = row0 + t;
    float z = ssum + ib2[0];
    float sig = 1.0f / (1.0f + expf(-z));
    f32x4 e4 = *(const f32x4*)(emo + (size_t)rowA * 4);
    float m4 = 0.25f * (e4[0] + e4[1] + e4[2] + e4[3]);
    out[(size_t)rowA * 6 + 5] = sig * m4;
  }

  // ---- E3: row norms from enc tile ----
  {
    int r = t >> 2, q = t & 3;
    int swz = (r & 7) << 4;
    float s = 0.f;
#pragma unroll
    for (int j = 0; j < 4; ++j) {
      uint4v u = *(const uint4v*)(sm + 32768 + ((r * 256 + q * 64 + j * 16) ^ swz));
#pragma unroll
      for (int e = 0; e < 4; ++e) {
        float lo = (float)(_Float16)__builtin_bit_cast(__fp16, (unsigned short)(u[e] & 0xFFFFu));
        float hi = (float)(_Float16)__builtin_bit_cast(__fp16, (unsigned short)(u[e] >> 16));
        s += lo * lo + hi * hi;
      }
    }
    s += __shfl_xor(s, 1);
    s += __shfl_xor(s, 2);
    if (q == 0) s_en[r] = sqrtf(s);
  }
  __syncthreads();

  float en[4];
#pragma unroll
  for (int r = 0; r < 4; ++r) en[r] = s_en[w * 16 + g * 4 + r];

  // A-frags for sims: wave w covers rows w*16..w*16+16, K=128, from enc tile
  half8 af2[4];
  {
    int row = w * 16 + c;
    int swz = (row & 7) << 4;
#pragma unroll
    for (int kk = 0; kk < 4; ++kk)
      af2[kk] = *(const half8*)(sm + 32768 + ((row * 256 + kk * 64 + g * 16) ^ swz));
  }

  unsigned int top5[4][5];
#pragma unroll
  for (int r = 0; r < 4; ++r)
#pragma unroll
    for (int s5 = 0; s5 < 5; ++s5) top5[r][s5] = 0u;

#pragma unroll
  for (int ch = 0; ch < 4; ++ch) {
    f32x4 acc[8];
#pragma unroll
    for (int i = 0; i < 8; ++i) acc[i] = f32x4{0.f, 0.f, 0.f, 0.f};
#pragma unroll
    for (int nfc = 0; nfc < 8; ++nfc) {
      const unsigned short* bb = centC + (size_t)(ch * 128 + nfc * 16 + c) * 128 + g * 8;
#pragma unroll
      for (int kk = 0; kk < 4; ++kk) {
        half8 bf = *(const half8*)(bb + kk * 32);
        acc[nfc] = mfma16(af2[kk], bf, acc[nfc]);
      }
    }
#pragma unroll
    for (int nfc = 0; nfc < 8; ++nfc) {
      int col = ch * 128 + nfc * 16 + c;
      float cnv = c_n[col];
#pragma unroll
      for (int r = 0; r < 4; ++r) {
        float denom = fmaxf(en[r] * cnv, 1e-8f);
        float v = acc[nfc][r] * __builtin_amdgcn_rcpf(denom);
        unsigned int u = __float_as_uint(v);
        u = (u & 0x80000000u) ? ~u : (u | 0x80000000u);
        unsigned int k = (col < 500) ? ((u & 0xFFFFFE00u) | (unsigned)col) : 0u;
        unsigned int t0 = top5[r][0], t1 = top5[r][1], t2 = top5[r][2],
                     t3 = top5[r][3], t4 = top5[r][4];
        top5[r][0] = (k > t0) ? k : t0;
        top5[r][1] = (k > t0) ? t0 : ((k > t1) ? k : t1);
        top5[r][2] = (k > t1) ? t1 : ((k > t2) ? k : t2);
        top5[r][3] = (k > t2) ? t2 : ((k > t3) ? k : t3);
        top5[r][4] = (k > t3) ? t3 : ((k > t4) ? k : t4);
      }
    }
  }

#pragma unroll
  for (int r = 0; r < 4; ++r) {
    int rowA = row0 + w * 16 + g * 4 + r;
    unsigned int h0 = top5[r][0], h1 = top5[r][1], h2 = top5[r][2],
                 h3 = top5[r][3], h4 = top5[r][4];
#pragma unroll
    for (int it5 = 0; it5 < 5; ++it5) {
      unsigned int best = h0;
#pragma unroll
      for (int s = 1; s < 16; s <<= 1) {
        unsigned int o = __shfl_xor(best, s);
        best = (o > best) ? o : best;
      }
      if (c == 0) {
        unsigned int m = best & 0xFFFFFE00u;
        unsigned int uu = (m & 0x80000000u) ? (m ^ 0x80000000u) : ~m;
        out[(size_t)rowA * 6 + it5] = __uint_as_float(uu);
      }
      bool pop = (h0 == best);
      h0 = pop ? h1 : h0;
      h1 = pop ? h2 : h1;
      h2 = pop ? h3 : h2;
      h3 = pop ? h4 : h3;
      h4 = pop ? 0u : h4;
    }
  }
}

// ---------------------------------------------------------------------------
extern "C" void kernel_launch(void* const* d_in, const int* in_sizes, int n_in,
                              void* d_out, int out_size, void* d_ws, size_t ws_size,
                              hipStream_t stream) {
  (void)in_sizes; (void)n_in; (void)out_size; (void)ws_size;
  const float* cue      = (const float*)d_in[0];
  const float* internal = (const float*)d_in[1];
  const float* reward   = (const float*)d_in[2];
  const float* tsp      = (const float*)d_in[3];
  const float* emo      = (const float*)d_in[4];
  const float* cent     = (const float*)d_in[5];
  const float* enc_w1   = (const float*)d_in[6];
  const float* enc_b1   = (const float*)d_in[7];
  const float* enc_w2   = (const float*)d_in[8];
  const float* enc_b2   = (const float*)d_in[9];
  const float* imp_w1   = (const float*)d_in[10];
  const float* imp_b1   = (const float*)d_in[11];
  const float* imp_w2   = (const float*)d_in[12];
  const float* imp_b2   = (const float*)d_in[13];
  float* out = (float*)d_out;

  unsigned char* ws = (unsigned char*)d_ws;
  unsigned short* W1T    = (unsigned short*)(ws + 0);        // 256*768*2 = 393216
  unsigned short* W2T    = (unsigned short*)(ws + 393216);   // 128*256*2 =  65536
  unsigned short* impW1T = (unsigned short*)(ws + 458752);   // 64*960*2  = 122880
  unsigned short* centC  = (unsigned short*)(ws + 581632);   // 512*128*2 = 131072
  float*          c_n    = (float*)(ws + 712704);            // 512*4     =   2048
  unsigned short* tail   = (unsigned short*)(ws + 714752);   // 32768*8*2 = 524288

  k_prep<<<768, 256, 0, stream>>>(enc_w1, enc_w2, imp_w1, cent, reward, tsp, emo,
                                  W1T, W2T, impW1T, centC, c_n, tail);
  k_mega<<<512, 256, 0, stream>>>(cue, internal, emo, W1T, W2T, impW1T, centC,
                                  tail, c_n, enc_b1, enc_b2, imp_b1, imp_w2,
                                  imp_b2, out);
}

// Round 5
// 109.093 us; speedup vs baseline: 1.9355x; 1.9355x over previous
//
#include <hip/hip_runtime.h>
#include <hip/hip_bf16.h>
#include <hip/hip_fp16.h>
#include <math.h>

// ---- types ----
using f32x4  = __attribute__((ext_vector_type(4))) float;
using half8  = __attribute__((ext_vector_type(8))) _Float16;
using uint4v = __attribute__((ext_vector_type(4))) unsigned int;

#define WAITV(N) asm volatile("s_waitcnt vmcnt(" #N ")" ::: "memory")
#define SCHB __builtin_amdgcn_sched_barrier(0)
#define BARRIER do { asm volatile("s_waitcnt lgkmcnt(0)" ::: "memory"); \
                     __builtin_amdgcn_sched_barrier(0); \
                     __builtin_amdgcn_s_barrier(); } while (0)

__device__ __forceinline__ unsigned short f32_to_f16u(float f) {
  return __half_as_ushort(__float2half(f));
}
__device__ __forceinline__ float f16u_to_f32(unsigned short h) {
  return __half2float(__ushort_as_half(h));
}
__device__ __forceinline__ unsigned int pk2(float a, float b) {
  return (unsigned int)f32_to_f16u(a) | ((unsigned int)f32_to_f16u(b) << 16);
}
__device__ __forceinline__ f32x4 mfma16(half8 a, half8 b, f32x4 c) {
  return __builtin_amdgcn_mfma_f32_16x16x32_f16(a, b, c, 0, 0, 0);
}
__device__ __forceinline__ void gload_lds16(void* lds, const void* g) {
  __builtin_amdgcn_global_load_lds(
      (const __attribute__((address_space(1))) unsigned int*)g,
      (__attribute__((address_space(3))) unsigned int*)lds, 16, 0, 0);
}
__device__ __forceinline__ float gelu_exact(float x) {
  return 0.5f * x * (1.0f + erff(x * 0.70710678118654752440f));
}

// ---- problem constants ----
// B=32768, D=768, H1=256, E=128, N=500(pad 512), K_imp=902(pad 960)

// ---------------------------------------------------------------------------
// prep: weight transposes -> f16 [N][K] row-major; centroid pad + norms;
// packed f16 tail[B][8] = {reward, ts, emo0..3, 0, 0}  (k 896..903)
// ---------------------------------------------------------------------------
__global__ __launch_bounds__(256) void k_prep(
    const float* __restrict__ enc_w1, const float* __restrict__ enc_w2,
    const float* __restrict__ imp_w1, const float* __restrict__ cent,
    const float* __restrict__ reward, const float* __restrict__ tsp,
    const float* __restrict__ emo,
    unsigned short* __restrict__ W1T, unsigned short* __restrict__ W2T,
    unsigned short* __restrict__ impW1T, unsigned short* __restrict__ centC,
    float* __restrict__ c_n, unsigned short* __restrict__ tail) {
  int idx = blockIdx.x * 256 + threadIdx.x;
  if (idx < 256 * 768) {               // W1T [256][768]
    int n = idx / 768, k = idx - n * 768;
    W1T[idx] = f32_to_f16u(enc_w1[k * 256 + n]);
  }
  if (idx < 128 * 256) {               // W2T [128][256]
    int n = idx >> 8, k = idx & 255;
    W2T[idx] = f32_to_f16u(enc_w2[k * 128 + n]);
  }
  if (idx < 64 * 960) {                // impW1T [64][960], k>=902 zero
    int n = idx / 960, k = idx - n * 960;
    impW1T[idx] = (k < 902) ? f32_to_f16u(imp_w1[k * 64 + n]) : (unsigned short)0;
  }
  if (idx < 512 * 128) {               // centC [512][128], rows>=500 zero
    int n = idx >> 7, k = idx & 127;
    centC[idx] = (n < 500) ? f32_to_f16u(cent[n * 128 + k]) : (unsigned short)0;
  }
  if (idx < 512) {                     // centroid norms (of f16-rounded values)
    float s = 0.f;
    if (idx < 500) {
      const f32x4* p = (const f32x4*)(cent + idx * 128);
#pragma unroll 8
      for (int j = 0; j < 32; ++j) {
        f32x4 v = p[j];
#pragma unroll
        for (int e = 0; e < 4; ++e) {
          float q = (float)(_Float16)v[e];
          s += q * q;
        }
      }
    }
    c_n[idx] = sqrtf(s);
  }
  if (idx < 32768) {                   // tail pack
    f32x4 e4 = *(const f32x4*)(emo + (size_t)idx * 4);
    unsigned short* tp = tail + (size_t)idx * 8;
    tp[0] = f32_to_f16u(reward[idx]);
    tp[1] = f32_to_f16u(tsp[idx]);
    tp[2] = f32_to_f16u(e4[0]); tp[3] = f32_to_f16u(e4[1]);
    tp[4] = f32_to_f16u(e4[2]); tp[5] = f32_to_f16u(e4[3]);
    tp[6] = 0; tp[7] = 0;
  }
}

// ---------------------------------------------------------------------------
// mega: whole op, 128 rows/block, 256 blocks, 512 thr (8 waves, wr=w>>2 wc=w&3)
// Main loop: 15 K-steps of 64.  A dbuf (2x16K), B1 tribuf (3x32K), B2 tribuf
// (3x8K) = 152KB LDS.  Counted vmcnt (never 0 in the 12 cue steps): waits
// leave the next tile's 9 loads in flight across every barrier.
// Epilogue (aliased LDS): h1 tile -> enc2 -> enc tile -> norms/sims/top5 +
// imp head.
// ---------------------------------------------------------------------------
__global__ __launch_bounds__(512, 2) void k_mega(
    const float* __restrict__ cue, const float* __restrict__ internal,
    const float* __restrict__ emo,
    const unsigned short* __restrict__ W1T, const unsigned short* __restrict__ W2T,
    const unsigned short* __restrict__ impW1T, const unsigned short* __restrict__ centC,
    const unsigned short* __restrict__ tail, const float* __restrict__ c_n,
    const float* __restrict__ b1, const float* __restrict__ b2,
    const float* __restrict__ ib1, const float* __restrict__ iw2,
    const float* __restrict__ ib2, float* __restrict__ out) {
  __shared__ unsigned char sm[155648];
  // A bufs:  [0,16K) [16K,32K)
  // B1 bufs: [32K,64K) [64K,96K) [96K,128K)
  // B2 bufs: [128K,136K) [136K,144K) [144K,152K)
  // epilogue alias: h1 [0,64K); enc [64K,96K); s_p [96K,98K); s_en [98K+2K..);
  //                 centroid chunks dbuf [0,64K)
  const int t = threadIdx.x;
  const int lane = t & 63, w = t >> 6;
  const int wr = w >> 2, wc = w & 3;
  const int g = lane >> 4, c = lane & 15;
  const int row0 = blockIdx.x * 128;

  // A staging: thread -> (row srow, 16-col quarter q)
  const int srow = t >> 2, q = t & 3;
  const int abyte = srow * 128 + q * 32;
  const int aswz = (srow & 7) << 4;
  const int myrow = row0 + srow;

  f32x4 a0A, a1A, a2A, a3A, a0B, a1B, a2B, a3B;

#define ISSUE_A_CUE(j, S) { const float* _s = cue + (size_t)myrow * 768 + (j) * 64 + q * 16; \
    a0##S = *(const f32x4*)(_s);     a1##S = *(const f32x4*)(_s + 4);  \
    a2##S = *(const f32x4*)(_s + 8); a3##S = *(const f32x4*)(_s + 12); }
#define ISSUE_A_INT(j, S) { const float* _s = internal + (size_t)myrow * 128 + ((j) - 12) * 64 + q * 16; \
    a0##S = *(const f32x4*)(_s);     a1##S = *(const f32x4*)(_s + 4);  \
    a2##S = *(const f32x4*)(_s + 8); a3##S = *(const f32x4*)(_s + 12); }
#define CONVW(S, abuf) { \
    unsigned char* _b = sm + (abuf) * 16384; \
    uint4v _u0 = {pk2(a0##S[0], a0##S[1]), pk2(a0##S[2], a0##S[3]), \
                  pk2(a1##S[0], a1##S[1]), pk2(a1##S[2], a1##S[3])}; \
    uint4v _u1 = {pk2(a2##S[0], a2##S[1]), pk2(a2##S[2], a2##S[3]), \
                  pk2(a3##S[0], a3##S[1]), pk2(a3##S[2], a3##S[3])}; \
    *(uint4v*)(_b + (abyte ^ aswz)) = _u0; \
    *(uint4v*)(_b + ((abyte + 16) ^ aswz)) = _u1; }

  auto issueB1 = [&](int j, int buf) {
#pragma unroll
    for (int i = 0; i < 4; ++i) {
      int L = i * 8192 + t * 16;
      int nl = L >> 7, x = L & 127;
      const unsigned char* gs = (const unsigned char*)W1T +
          ((size_t)nl * 768 + j * 64) * 2 + (x ^ ((nl & 7) << 4));
      gload_lds16(sm + 32768 + buf * 32768 + i * 8192 + w * 1024, gs);
    }
  };
  auto issueB2 = [&](int j, int buf) {
    int L = t * 16;
    int nl = L >> 7, x = L & 127;
    const unsigned char* gs = (const unsigned char*)impW1T +
        (size_t)nl * 1920 + j * 128 + (x ^ ((nl & 7) << 4));
    gload_lds16(sm + 131072 + buf * 8192 + w * 1024, gs);
  };

  f32x4 acc1[4][4];
  f32x4 acc2[4];
#pragma unroll
  for (int i = 0; i < 4; ++i) {
    acc2[i] = f32x4{0.f, 0.f, 0.f, 0.f};
#pragma unroll
    for (int j = 0; j < 4; ++j) acc1[i][j] = f32x4{0.f, 0.f, 0.f, 0.f};
  }

  auto mfma_step = [&](int abuf, int bbuf, bool enc) {
    const unsigned char* Ab  = sm + abuf * 16384;
    const unsigned char* Bb1 = sm + 32768 + bbuf * 32768;
    const unsigned char* Bb2 = sm + 131072 + bbuf * 8192;
#pragma unroll
    for (int ks = 0; ks < 2; ++ks) {
      half8 af[4];
#pragma unroll
      for (int mf = 0; mf < 4; ++mf) {
        int m = wr * 64 + mf * 16 + c;
        af[mf] = *(const half8*)(Ab + m * 128 + ((ks * 64 + g * 16) ^ ((m & 7) << 4)));
      }
      {
        int n2 = wc * 16 + c;
        half8 b2f = *(const half8*)(Bb2 + n2 * 128 + ((ks * 64 + g * 16) ^ ((n2 & 7) << 4)));
#pragma unroll
        for (int mf = 0; mf < 4; ++mf) acc2[mf] = mfma16(af[mf], b2f, acc2[mf]);
      }
      if (enc) {
#pragma unroll
        for (int nf = 0; nf < 4; ++nf) {
          int n = wc * 64 + nf * 16 + c;
          half8 bf = *(const half8*)(Bb1 + n * 128 + ((ks * 64 + g * 16) ^ ((n & 7) << 4)));
#pragma unroll
          for (int mf = 0; mf < 4; ++mf) acc1[mf][nf] = mfma16(af[mf], bf, acc1[mf][nf]);
        }
      }
    }
  };

  // ---- prologue: tiles 0,1,2 issued; tile0 A staged ----
  ISSUE_A_CUE(0, A); issueB1(0, 0); issueB2(0, 0);
  ISSUE_A_CUE(1, B); issueB1(1, 1); issueB2(1, 1);
  CONVW(A, 0);                       // consumes A(0) regs (auto vmcnt)
  ISSUE_A_CUE(2, A); issueB1(2, 2); issueB2(2, 2);
  WAITV(18);                         // B(0) in LDS; A1,B1,A2,B2 still flying
  BARRIER;

  // ---- main pipelined loop: tiles 0..11 (cue) ----
#pragma unroll
  for (int j = 0; j < 12; ++j) {
    mfma_step(j & 1, j % 3, true);
    if ((j & 1) == 0) { CONVW(B, (j + 1) & 1); } else { CONVW(A, (j + 1) & 1); }
    if (j <= 9) { WAITV(9); } else { WAITV(5); }   // B(j+1) landed; j+2 flying
    BARRIER;
    if (j <= 8) {
      if ((j & 1) == 0) { ISSUE_A_CUE(j + 3, B); } else { ISSUE_A_CUE(j + 3, A); }
      issueB1(j + 3, j % 3); issueB2(j + 3, j % 3);
    } else if (j <= 10) {
      if ((j & 1) == 0) { ISSUE_A_INT(j + 3, B); } else { ISSUE_A_INT(j + 3, A); }
      issueB2(j + 3, j % 3);
    } else {
      issueB2(14, 2);
    }
  }

  // ---- tiles 12,13 (internal), 14 (tail): imp only ----
  mfma_step(0, 0, false);            // tile 12
  CONVW(B, 1);                       // tile 13 -> abuf1
  WAITV(1);
  BARRIER;
  mfma_step(1, 1, false);            // tile 13
  {                                  // tile 14 A: tail (k 896..903), rest 0
    uint4v tl = *(const uint4v*)(tail + (size_t)myrow * 8);
    uint4v z = {0u, 0u, 0u, 0u};
    unsigned char* _b = sm;          // abuf0
    *(uint4v*)(_b + (abyte ^ aswz)) = (q == 0) ? tl : z;
    *(uint4v*)(_b + ((abyte + 16) ^ aswz)) = z;
  }
  WAITV(0);
  BARRIER;
  mfma_step(0, 2, false);            // tile 14
  __syncthreads();

  // ---- E1: bias + gelu -> h1 tile [128][256] f16 swizzled at [0,64K) ----
  {
    float bias1[4];
#pragma unroll
    for (int nf = 0; nf < 4; ++nf) bias1[nf] = b1[wc * 64 + nf * 16 + c];
#pragma unroll
    for (int mf = 0; mf < 4; ++mf)
#pragma unroll
      for (int nf = 0; nf < 4; ++nf)
#pragma unroll
        for (int rr = 0; rr < 4; ++rr) {
          int row = wr * 64 + mf * 16 + g * 4 + rr;
          int col = wc * 64 + nf * 16 + c;
          float x = gelu_exact(acc1[mf][nf][rr] + bias1[nf]);
          int byte = (row * 512 + col * 2) ^ ((row & 7) << 4);
          *(unsigned short*)(sm + byte) = f32_to_f16u(x);
        }
  }
  __syncthreads();

  // ---- E2: enc2 GEMM (K=256) from h1 tile; B=W2T direct (L2-hot) ----
  const int wr2 = w & 1, wc2 = w >> 1;   // rows wr2*64.., cols wc2*32..
  {
    f32x4 acc3[4][2];
#pragma unroll
    for (int i = 0; i < 4; ++i)
#pragma unroll
      for (int j = 0; j < 2; ++j) acc3[i][j] = f32x4{0.f, 0.f, 0.f, 0.f};
#pragma unroll
    for (int ks = 0; ks < 8; ++ks) {
      half8 a2[4];
#pragma unroll
      for (int mf = 0; mf < 4; ++mf) {
        int row = wr2 * 64 + mf * 16 + c;
        a2[mf] = *(const half8*)(sm + ((row * 512 + ks * 64 + g * 16) ^ ((row & 7) << 4)));
      }
#pragma unroll
      for (int nf2 = 0; nf2 < 2; ++nf2) {
        int n = wc2 * 32 + nf2 * 16 + c;
        half8 bf = *(const half8*)(W2T + (size_t)n * 256 + ks * 32 + g * 8);
#pragma unroll
        for (int mf = 0; mf < 4; ++mf) acc3[mf][nf2] = mfma16(a2[mf], bf, acc3[mf][nf2]);
      }
    }
    float b2v[2];
#pragma unroll
    for (int nf2 = 0; nf2 < 2; ++nf2) b2v[nf2] = b2[wc2 * 32 + nf2 * 16 + c];
#pragma unroll
    for (int mf = 0; mf < 4; ++mf)
#pragma unroll
      for (int nf2 = 0; nf2 < 2; ++nf2)
#pragma unroll
        for (int rr = 0; rr < 4; ++rr) {
          int row = wr2 * 64 + mf * 16 + g * 4 + rr;
          int col = wc2 * 32 + nf2 * 16 + c;
          float x = acc3[mf][nf2][rr] + b2v[nf2];
          int byte = (row * 256 + col * 2) ^ ((row & 7) << 4);
          *(unsigned short*)(sm + 65536 + byte) = f32_to_f16u(x);
        }
  }

  // ---- E4a: imp head partials (uses main-loop acc2) ----
  {
    float* s_p = (float*)(sm + 98304);
    float b1v = ib1[wc * 16 + c];
    float w2v = iw2[wc * 16 + c];
#pragma unroll
    for (int mf = 0; mf < 4; ++mf)
#pragma unroll
      for (int rr = 0; rr < 4; ++rr) {
        float v = gelu_exact(acc2[mf][rr] + b1v) * w2v;
        v += __shfl_xor(v, 1);
        v += __shfl_xor(v, 2);
        v += __shfl_xor(v, 4);
        v += __shfl_xor(v, 8);
        if (c == 0) s_p[(wr * 64 + mf * 16 + g * 4 + rr) * 4 + wc] = v;
      }
  }
  __syncthreads();

  // ---- centroid chunk staging (dbuf 2x32KB at [0,64K); h1 now dead) ----
  auto issueC = [&](int ch, int buf) {
#pragma unroll
    for (int i = 0; i < 4; ++i) {
      int L = i * 8192 + t * 16;
      int nl = L >> 8, x = L & 255;
      const unsigned char* gs = (const unsigned char*)centC +
          (size_t)(ch * 128 + nl) * 256 + (x ^ ((nl & 7) << 4));
      gload_lds16(sm + buf * 32768 + i * 8192 + w * 1024, gs);
    }
  };
  issueC(0, 0);

  // ---- E3: row norms from enc tile ----
  {
    float* s_en = (float*)(sm + 100352);
    int r = t >> 2, q2 = t & 3;
    int swz = (r & 7) << 4;
    float s = 0.f;
#pragma unroll
    for (int jj = 0; jj < 4; ++jj) {
      uint4v u = *(const uint4v*)(sm + 65536 + ((r * 256 + q2 * 64 + jj * 16) ^ swz));
#pragma unroll
      for (int e = 0; e < 4; ++e) {
        float lo = f16u_to_f32((unsigned short)(u[e] & 0xFFFFu));
        float hi = f16u_to_f32((unsigned short)(u[e] >> 16));
        s += lo * lo + hi * hi;
      }
    }
    s += __shfl_xor(s, 1);
    s += __shfl_xor(s, 2);
    if (q2 == 0) s_en[r] = sqrtf(s);
  }

  // ---- E4b: imp final ----
  if (t < 128) {
    const float* s_p = (const float*)(sm + 98304);
    float ssum = s_p[t * 4 + 0] + s_p[t * 4 + 1] + s_p[t * 4 + 2] + s_p[t * 4 + 3];
    int rowA = row0 + t;
    float z = ssum + ib2[0];
    float sig = 1.0f / (1.0f + expf(-z));
    f32x4 e4 = *(const f32x4*)(emo + (size_t)rowA * 4);
    float m4 = 0.25f * (e4[0] + e4[1] + e4[2] + e4[3]);
    out[(size_t)rowA * 6 + 5] = sig * m4;
  }

  WAITV(0);          // chunk0 landed
  __syncthreads();   // + s_en visible

  // ---- E5: sims + streaming top-5 (wave w: rows w*16..w*16+16) ----
  float en[4];
  {
    const float* s_en = (const float*)(sm + 100352);
#pragma unroll
    for (int r = 0; r < 4; ++r) en[r] = s_en[w * 16 + g * 4 + r];
  }
  half8 af2[4];
  {
    int row = w * 16 + c;
    int swz = (row & 7) << 4;
#pragma unroll
    for (int kk = 0; kk < 4; ++kk)
      af2[kk] = *(const half8*)(sm + 65536 + ((row * 256 + kk * 64 + g * 16) ^ swz));
  }

  unsigned int top5[4][5];
#pragma unroll
  for (int r = 0; r < 4; ++r)
#pragma unroll
    for (int s5 = 0; s5 < 5; ++s5) top5[r][s5] = 0u;

#pragma unroll
  for (int ch = 0; ch < 4; ++ch) {
    if (ch < 3) issueC(ch + 1, (ch + 1) & 1);
    const unsigned char* Cb = sm + (ch & 1) * 32768;
    f32x4 acc[8];
#pragma unroll
    for (int i = 0; i < 8; ++i) acc[i] = f32x4{0.f, 0.f, 0.f, 0.f};
#pragma unroll
    for (int nfc = 0; nfc < 8; ++nfc) {
      int nl = nfc * 16 + c;
      const unsigned char* bb = Cb + nl * 256;
      int swz = (nl & 7) << 4;
#pragma unroll
      for (int kk = 0; kk < 4; ++kk) {
        half8 bf = *(const half8*)(bb + ((kk * 64 + g * 16) ^ swz));
        acc[nfc] = mfma16(af2[kk], bf, acc[nfc]);
      }
    }
#pragma unroll
    for (int nfc = 0; nfc < 8; ++nfc) {
      int col = ch * 128 + nfc * 16 + c;
      float cnv = c_n[col];
#pragma unroll
      for (int r = 0; r < 4; ++r) {
        float denom = fmaxf(en[r] * cnv, 1e-8f);
        float v = acc[nfc][r] * __builtin_amdgcn_rcpf(denom);
        unsigned int u = __float_as_uint(v);
        u = (u & 0x80000000u) ? ~u : (u | 0x80000000u);
        unsigned int k = (col < 500) ? ((u & 0xFFFFFE00u) | (unsigned)col) : 0u;
        unsigned int t0 = top5[r][0], t1 = top5[r][1], t2 = top5[r][2],
                     t3 = top5[r][3], t4 = top5[r][4];
        top5[r][0] = (k > t0) ? k : t0;
        top5[r][1] = (k > t0) ? t0 : ((k > t1) ? k : t1);
        top5[r][2] = (k > t1) ? t1 : ((k > t2) ? k : t2);
        top5[r][3] = (k > t2) ? t2 : ((k > t3) ? k : t3);
        top5[r][4] = (k > t3) ? t3 : ((k > t4) ? k : t4);
      }
    }
    WAITV(0);
    BARRIER;
  }

#pragma unroll
  for (int r = 0; r < 4; ++r) {
    int rowA = row0 + w * 16 + g * 4 + r;
    unsigned int h0 = top5[r][0], h1 = top5[r][1], h2 = top5[r][2],
                 h3 = top5[r][3], h4 = top5[r][4];
#pragma unroll
    for (int it5 = 0; it5 < 5; ++it5) {
      unsigned int best = h0;
#pragma unroll
      for (int s = 1; s < 16; s <<= 1) {
        unsigned int o = __shfl_xor(best, s);
        best = (o > best) ? o : best;
      }
      if (c == 0) {
        unsigned int m = best & 0xFFFFFE00u;
        unsigned int uu = (m & 0x80000000u) ? (m ^ 0x80000000u) : ~m;
        out[(size_t)rowA * 6 + it5] = __uint_as_float(uu);
      }
      bool pop = (h0 == best);
      h0 = pop ? h1 : h0;
      h1 = pop ? h2 : h1;
      h2 = pop ? h3 : h2;
      h3 = pop ? h4 : h3;
      h4 = pop ? 0u : h4;
    }
  }
}

// ---------------------------------------------------------------------------
extern "C" void kernel_launch(void* const* d_in, const int* in_sizes, int n_in,
                              void* d_out, int out_size, void* d_ws, size_t ws_size,
                              hipStream_t stream) {
  (void)in_sizes; (void)n_in; (void)out_size; (void)ws_size;
  const float* cue      = (const float*)d_in[0];
  const float* internal = (const float*)d_in[1];
  const float* reward   = (const float*)d_in[2];
  const float* tsp      = (const float*)d_in[3];
  const float* emo      = (const float*)d_in[4];
  const float* cent     = (const float*)d_in[5];
  const float* enc_w1   = (const float*)d_in[6];
  const float* enc_b1   = (const float*)d_in[7];
  const float* enc_w2   = (const float*)d_in[8];
  const float* enc_b2   = (const float*)d_in[9];
  const float* imp_w1   = (const float*)d_in[10];
  const float* imp_b1   = (const float*)d_in[11];
  const float* imp_w2   = (const float*)d_in[12];
  const float* imp_b2   = (const float*)d_in[13];
  float* out = (float*)d_out;

  unsigned char* ws = (unsigned char*)d_ws;
  unsigned short* W1T    = (unsigned short*)(ws + 0);        // 256*768*2 = 393216
  unsigned short* W2T    = (unsigned short*)(ws + 393216);   // 128*256*2 =  65536
  unsigned short* impW1T = (unsigned short*)(ws + 458752);   // 64*960*2  = 122880
  unsigned short* centC  = (unsigned short*)(ws + 581632);   // 512*128*2 = 131072
  float*          c_n    = (float*)(ws + 712704);            // 512*4     =   2048
  unsigned short* tail   = (unsigned short*)(ws + 714752);   // 32768*8*2 = 524288

  k_prep<<<768, 256, 0, stream>>>(enc_w1, enc_w2, imp_w1, cent, reward, tsp, emo,
                                  W1T, W2T, impW1T, centC, c_n, tail);
  k_mega<<<256, 512, 0, stream>>>(cue, internal, emo, W1T, W2T, impW1T, centC,
                                  tail, c_n, enc_b1, enc_b2, imp_b1, imp_w2,
                                  imp_b2, out);
}

// Round 6
// 74.370 us; speedup vs baseline: 2.8392x; 1.4669x over previous
//
#include <hip/hip_runtime.h>
#include <hip/hip_bf16.h>
#include <hip/hip_fp16.h>
#include <math.h>

// ---- types ----
using f32x4  = __attribute__((ext_vector_type(4))) float;
using half8  = __attribute__((ext_vector_type(8))) _Float16;
using uint4v = __attribute__((ext_vector_type(4))) unsigned int;

#define WAITV(N) asm volatile("s_waitcnt vmcnt(" #N ")" ::: "memory")
#define LGKM0    asm volatile("s_waitcnt lgkmcnt(0)" ::: "memory")

__device__ __forceinline__ unsigned short f32_to_f16u(float f) {
  return __half_as_ushort(__float2half(f));
}
__device__ __forceinline__ float f16u_to_f32(unsigned short h) {
  return __half2float(__ushort_as_half(h));
}
__device__ __forceinline__ unsigned int pk2(float a, float b) {
  return (unsigned int)f32_to_f16u(a) | ((unsigned int)f32_to_f16u(b) << 16);
}
__device__ __forceinline__ f32x4 mfma16(half8 a, half8 b, f32x4 c) {
  return __builtin_amdgcn_mfma_f32_16x16x32_f16(a, b, c, 0, 0, 0);
}
__device__ __forceinline__ void gload_lds16(void* lds, const void* g) {
  __builtin_amdgcn_global_load_lds(
      (const __attribute__((address_space(1))) unsigned int*)g,
      (__attribute__((address_space(3))) unsigned int*)lds, 16, 0, 0);
}
__device__ __forceinline__ float gelu_exact(float x) {
  return 0.5f * x * (1.0f + erff(x * 0.70710678118654752440f));
}

// ---- problem constants ----
// B=32768, D=768, H1=256, E=128, N=500(pad 512), K_imp=902(pad 960)

// ---------------------------------------------------------------------------
// prep: weight transposes -> f16 [N][K] row-major; centroid pad + norms;
// packed f16 tail[B][8] = {reward, ts, emo0..3, 0, 0}  (k 896..903)
// ---------------------------------------------------------------------------
__global__ __launch_bounds__(256) void k_prep(
    const float* __restrict__ enc_w1, const float* __restrict__ enc_w2,
    const float* __restrict__ imp_w1, const float* __restrict__ cent,
    const float* __restrict__ reward, const float* __restrict__ tsp,
    const float* __restrict__ emo,
    unsigned short* __restrict__ W1T, unsigned short* __restrict__ W2T,
    unsigned short* __restrict__ impW1T, unsigned short* __restrict__ centC,
    float* __restrict__ c_n, unsigned short* __restrict__ tail) {
  int idx = blockIdx.x * 256 + threadIdx.x;
  if (idx < 256 * 768) {               // W1T [256][768]
    int n = idx / 768, k = idx - n * 768;
    W1T[idx] = f32_to_f16u(enc_w1[k * 256 + n]);
  }
  if (idx < 128 * 256) {               // W2T [128][256]
    int n = idx >> 8, k = idx & 255;
    W2T[idx] = f32_to_f16u(enc_w2[k * 128 + n]);
  }
  if (idx < 64 * 960) {                // impW1T [64][960], k>=902 zero
    int n = idx / 960, k = idx - n * 960;
    impW1T[idx] = (k < 902) ? f32_to_f16u(imp_w1[k * 64 + n]) : (unsigned short)0;
  }
  if (idx < 512 * 128) {               // centC [512][128], rows>=500 zero
    int n = idx >> 7, k = idx & 127;
    centC[idx] = (n < 500) ? f32_to_f16u(cent[n * 128 + k]) : (unsigned short)0;
  }
  if (idx < 512) {                     // centroid norms (of f16-rounded values)
    float s = 0.f;
    if (idx < 500) {
      const f32x4* p = (const f32x4*)(cent + idx * 128);
#pragma unroll 8
      for (int j = 0; j < 32; ++j) {
        f32x4 v = p[j];
#pragma unroll
        for (int e = 0; e < 4; ++e) {
          float q = (float)(_Float16)v[e];
          s += q * q;
        }
      }
    }
    c_n[idx] = sqrtf(s);
  }
  if (idx < 32768) {                   // tail pack
    f32x4 e4 = *(const f32x4*)(emo + (size_t)idx * 4);
    unsigned short* tp = tail + (size_t)idx * 8;
    tp[0] = f32_to_f16u(reward[idx]);
    tp[1] = f32_to_f16u(tsp[idx]);
    tp[2] = f32_to_f16u(e4[0]); tp[3] = f32_to_f16u(e4[1]);
    tp[4] = f32_to_f16u(e4[2]); tp[5] = f32_to_f16u(e4[3]);
    tp[6] = 0; tp[7] = 0;
  }
}

// ---------------------------------------------------------------------------
// fused enc1+imp, 64 rows/block, 512 blocks (2 blocks/CU!), 512 thr (8 waves).
// Wave w (wr=w>>2, wc=w&3): enc 32x64 (acc1 2x4), imp 32x16 (acc2 2).
// LDS 72KB: A dbuf 2x8K | tail slot 8K | B1 single 32K | B2 dbuf 2x8K.
// 15 K-steps of 64. Counted vmcnt(3): A(it+2) regs + B2(it+2) stay in flight
// across barriers; single-buffered B1 staged in the inter-barrier window,
// covered by the co-resident sibling block (m114-style TLP).
// ---------------------------------------------------------------------------
__global__ __launch_bounds__(512, 4) void k_encimp(
    const float* __restrict__ cue, const float* __restrict__ internal,
    const float* __restrict__ emo,
    const unsigned short* __restrict__ W1T, const unsigned short* __restrict__ impW1T,
    const unsigned short* __restrict__ tail,
    const float* __restrict__ b1, const float* __restrict__ ib1,
    const float* __restrict__ iw2, const float* __restrict__ ib2,
    unsigned short* __restrict__ h1, float* __restrict__ out) {
  __shared__ unsigned char sm[73728];
  const int t = threadIdx.x;
  const int lane = t & 63, w = t >> 6;
  const int wr = w >> 2, wc = w & 3;
  const int g = lane >> 4, c = lane & 15;
  const int row0 = blockIdx.x * 64;

  // A staging: thread -> (row srow = t>>3, 8-col slot q8 = t&7), 16 B each
  const int srow = t >> 3, q8 = t & 7;
  const int abyte = srow * 128 + q8 * 16;
  const int aswz = (srow & 7) << 4;
  const int myrow = row0 + srow;

  f32x4 aLo, aHi;
  auto issueA = [&](int j) {
    const float* s = (j < 12)
        ? (cue + (size_t)myrow * 768 + j * 64 + q8 * 8)
        : (internal + (size_t)myrow * 128 + (j - 12) * 64 + q8 * 8);
    aLo = *(const f32x4*)s;
    aHi = *(const f32x4*)(s + 4);
  };
  auto convWrite = [&](int buf) {
    uint4v u = {pk2(aLo[0], aLo[1]), pk2(aLo[2], aLo[3]),
                pk2(aHi[0], aHi[1]), pk2(aHi[2], aHi[3])};
    *(uint4v*)(sm + buf * 8192 + (abyte ^ aswz)) = u;
  };
  auto issueB1 = [&](int j) {
#pragma unroll
    for (int i = 0; i < 4; ++i) {
      int L = i * 8192 + t * 16;
      int nl = L >> 7, x = L & 127;
      gload_lds16(sm + 24576 + i * 8192 + w * 1024,
                  (const unsigned char*)W1T + ((size_t)nl * 768 + j * 64) * 2 +
                      (x ^ ((nl & 7) << 4)));
    }
  };
  auto issueB2 = [&](int j, int buf) {
    int L = t * 16, nl = L >> 7, x = L & 127;
    gload_lds16(sm + 57344 + buf * 8192 + w * 1024,
                (const unsigned char*)impW1T + (size_t)nl * 1920 + j * 128 +
                    (x ^ ((nl & 7) << 4)));
  };

  f32x4 acc1[2][4];
  f32x4 acc2[2];
#pragma unroll
  for (int i = 0; i < 2; ++i) {
    acc2[i] = f32x4{0.f, 0.f, 0.f, 0.f};
#pragma unroll
    for (int j = 0; j < 4; ++j) acc1[i][j] = f32x4{0.f, 0.f, 0.f, 0.f};
  }

  auto mfma_step = [&](int abuf, int b2buf, bool enc) {
    const unsigned char* Ab  = sm + abuf * 8192;
    const unsigned char* Bb2 = sm + 57344 + b2buf * 8192;
#pragma unroll
    for (int ks = 0; ks < 2; ++ks) {
      half8 af[2];
#pragma unroll
      for (int mf = 0; mf < 2; ++mf) {
        int m = wr * 32 + mf * 16 + c;
        af[mf] = *(const half8*)(Ab + m * 128 + ((ks * 64 + g * 16) ^ ((m & 7) << 4)));
      }
      {
        int n2 = wc * 16 + c;
        half8 b2f = *(const half8*)(Bb2 + n2 * 128 + ((ks * 64 + g * 16) ^ ((n2 & 7) << 4)));
        acc2[0] = mfma16(af[0], b2f, acc2[0]);
        acc2[1] = mfma16(af[1], b2f, acc2[1]);
      }
      if (enc) {
#pragma unroll
        for (int nf = 0; nf < 4; ++nf) {
          int n = wc * 64 + nf * 16 + c;
          half8 bf = *(const half8*)(sm + 24576 + n * 128 +
                                     ((ks * 64 + g * 16) ^ ((n & 7) << 4)));
          acc1[0][nf] = mfma16(af[0], bf, acc1[0][nf]);
          acc1[1][nf] = mfma16(af[1], bf, acc1[1][nf]);
        }
      }
    }
  };

  // ---- prologue: tail slot + tile0 staged; tile1 A/B2 in flight ----
  {
    uint4v tl = {0u, 0u, 0u, 0u};
    if (q8 == 0) tl = *(const uint4v*)(tail + (size_t)myrow * 8);
    issueA(0); issueB1(0); issueB2(0, 0);
    *(uint4v*)(sm + 16384 + (abyte ^ aswz)) = tl;   // tail tile (abuf index 2)
    convWrite(0);                                    // A(0) -> abuf0
    issueA(1); issueB2(1, 1);
    WAITV(3);                                        // B1(0),B2(0) landed
    LGKM0;
    __builtin_amdgcn_s_barrier();
  }

  int p = 0;
  for (int it = 0; it < 12; ++it) {
    mfma_step(p, p, true);
    convWrite(p ^ 1);                  // A(it+1) -> abuf p^1 (auto-waits regs)
    LGKM0;
    __builtin_amdgcn_s_barrier();      // #1: all reads of B1(it)/B2(p) done
    if (it < 11) issueB1(it + 1);      // overwrite B1 (single buffer)
    issueA(it + 2);                    // cue (<=11) or internal (12,13)
    issueB2(it + 2, p);                // overwrite b2buf p
    WAITV(3);                          // B1(it+1)+B2(it+1) landed; 3 in flight
    __builtin_amdgcn_s_barrier();      // #2
    p ^= 1;
  }
  // p == 0 here. Steps 12,13 (internal), 14 (tail): imp only.
  mfma_step(0, 0, false);              // tile 12
  convWrite(1);                        // A(13)
  LGKM0;
  __builtin_amdgcn_s_barrier();
  issueB2(14, 0);
  WAITV(1);                            // B2(13) landed
  __builtin_amdgcn_s_barrier();
  mfma_step(1, 1, false);              // tile 13
  LGKM0;
  __builtin_amdgcn_s_barrier();
  WAITV(0);                            // B2(14) landed
  __builtin_amdgcn_s_barrier();
  mfma_step(2, 0, false);              // tile 14 (tail slot)

  // ---- enc1 epilogue: bias + exact gelu -> h1 (global, f16) ----
  float bias1[4];
#pragma unroll
  for (int nf = 0; nf < 4; ++nf) bias1[nf] = b1[wc * 64 + nf * 16 + c];
#pragma unroll
  for (int mf = 0; mf < 2; ++mf)
#pragma unroll
    for (int nf = 0; nf < 4; ++nf)
#pragma unroll
      for (int rr = 0; rr < 4; ++rr) {
        float x = acc1[mf][nf][rr] + bias1[nf];
        int m = row0 + wr * 32 + mf * 16 + g * 4 + rr;
        int n = wc * 64 + nf * 16 + c;
        h1[(size_t)m * 256 + n] = f32_to_f16u(gelu_exact(x));
      }

  // ---- imp epilogue: gelu*w2, 16-lane reduce -> LDS partials -> final ----
  {
    float* s_p = (float*)(sm + 24576);  // B1 area, dead now
    float b1v = ib1[wc * 16 + c];
    float w2v = iw2[wc * 16 + c];
#pragma unroll
    for (int mf = 0; mf < 2; ++mf)
#pragma unroll
      for (int rr = 0; rr < 4; ++rr) {
        float v = gelu_exact(acc2[mf][rr] + b1v) * w2v;
        v += __shfl_xor(v, 1);
        v += __shfl_xor(v, 2);
        v += __shfl_xor(v, 4);
        v += __shfl_xor(v, 8);
        if (c == 0) s_p[(wr * 32 + mf * 16 + g * 4 + rr) * 4 + wc] = v;
      }
    __syncthreads();
    if (t < 64) {
      float ssum = s_p[t * 4 + 0] + s_p[t * 4 + 1] + s_p[t * 4 + 2] + s_p[t * 4 + 3];
      int rowA = row0 + t;
      float z = ssum + ib2[0];
      float sig = 1.0f / (1.0f + expf(-z));
      f32x4 e4 = *(const f32x4*)(emo + (size_t)rowA * 4);
      float m4 = 0.25f * (e4[0] + e4[1] + e4[2] + e4[3]);
      out[(size_t)rowA * 6 + 5] = sig * m4;
    }
  }
}

// ---------------------------------------------------------------------------
// enc2: enc = h1 @ W2 + b2   [32768,256]x[256,128] -> f16 [32768][128]
// ---------------------------------------------------------------------------
__global__ __launch_bounds__(256) void k_enc2(
    const unsigned short* __restrict__ h1, const unsigned short* __restrict__ W2T,
    const float* __restrict__ b2, unsigned short* __restrict__ enc) {
  __shared__ unsigned char smA[16384];
  __shared__ unsigned char smB[8192];
  const int t = threadIdx.x;
  const int lane = t & 63, w = t >> 6;
  const int wr = w >> 1, wc = w & 1;
  const int g = lane >> 4, c = lane & 15;
  const int row0 = blockIdx.x * 128;
  const int n0 = blockIdx.y * 64;

  f32x4 acc[4][2];
#pragma unroll
  for (int i = 0; i < 4; ++i)
#pragma unroll
    for (int j = 0; j < 2; ++j) acc[i][j] = f32x4{0.f, 0.f, 0.f, 0.f};

  for (int it = 0; it < 4; ++it) {
    __syncthreads();
#pragma unroll
    for (int i = 0; i < 4; ++i) {
      int L = i * 4096 + t * 16;
      int rl = L >> 7, x = L & 127;
      const unsigned char* gs = (const unsigned char*)h1 +
          (size_t)(row0 + rl) * 512 + it * 128 + (x ^ ((rl & 7) << 4));
      gload_lds16(smA + i * 4096 + w * 1024, gs);
    }
#pragma unroll
    for (int i = 0; i < 2; ++i) {
      int L = i * 4096 + t * 16;
      int nl = L >> 7, x = L & 127;
      const unsigned char* gs = (const unsigned char*)W2T +
          (size_t)(n0 + nl) * 512 + it * 128 + (x ^ ((nl & 7) << 4));
      gload_lds16(smB + i * 4096 + w * 1024, gs);
    }
    __syncthreads();
#pragma unroll
    for (int ks = 0; ks < 2; ++ks) {
      half8 af[4], bf[2];
#pragma unroll
      for (int mf = 0; mf < 4; ++mf) {
        int m = wr * 64 + mf * 16 + c;
        af[mf] = *(const half8*)(smA + m * 128 + (((ks * 64) + g * 16) ^ ((m & 7) << 4)));
      }
#pragma unroll
      for (int nf = 0; nf < 2; ++nf) {
        int n = wc * 32 + nf * 16 + c;
        bf[nf] = *(const half8*)(smB + n * 128 + (((ks * 64) + g * 16) ^ ((n & 7) << 4)));
      }
#pragma unroll
      for (int mf = 0; mf < 4; ++mf)
#pragma unroll
        for (int nf = 0; nf < 2; ++nf)
          acc[mf][nf] = mfma16(af[mf], bf[nf], acc[mf][nf]);
    }
  }
  float bias[2];
#pragma unroll
  for (int nf = 0; nf < 2; ++nf) bias[nf] = b2[n0 + wc * 32 + nf * 16 + c];
#pragma unroll
  for (int mf = 0; mf < 4; ++mf)
#pragma unroll
    for (int nf = 0; nf < 2; ++nf)
#pragma unroll
      for (int r = 0; r < 4; ++r) {
        float x = acc[mf][nf][r] + bias[nf];
        int m = row0 + wr * 64 + mf * 16 + g * 4 + r;
        int n = n0 + wc * 32 + nf * 16 + c;
        enc[(size_t)m * 128 + n] = f32_to_f16u(x);
      }
}

// ---------------------------------------------------------------------------
// sims + top5 (streaming): per block 64 rows; each wave 16 rows x 512 cols.
// ---------------------------------------------------------------------------
__global__ __launch_bounds__(256) void k_sims(
    const unsigned short* __restrict__ enc, const unsigned short* __restrict__ centC,
    const float* __restrict__ c_n, float* __restrict__ out) {
  __shared__ unsigned char smC[32768];
  __shared__ float s_en[64];
  const int t = threadIdx.x, lane = t & 63, w = t >> 6;
  const int g = lane >> 4, c = lane & 15;
  const int row0 = blockIdx.x * 64;

  {
    int r = t >> 2, q = t & 3;
    const unsigned char* base = (const unsigned char*)enc + (size_t)(row0 + r) * 256 + q * 64;
    float s = 0.f;
#pragma unroll
    for (int j = 0; j < 4; ++j) {
      uint4v u = *(const uint4v*)(base + j * 16);
#pragma unroll
      for (int e = 0; e < 4; ++e) {
        float lo = f16u_to_f32((unsigned short)(u[e] & 0xFFFFu));
        float hi = f16u_to_f32((unsigned short)(u[e] >> 16));
        s += lo * lo + hi * hi;
      }
    }
    s += __shfl_xor(s, 1);
    s += __shfl_xor(s, 2);
    if (q == 0) s_en[r] = sqrtf(s);
  }
  __syncthreads();

  float en[4];
#pragma unroll
  for (int r = 0; r < 4; ++r) en[r] = s_en[w * 16 + g * 4 + r];

  half8 af[4];
  {
    const unsigned char* abase =
        (const unsigned char*)enc + (size_t)(row0 + w * 16 + c) * 256 + g * 16;
#pragma unroll
    for (int kk = 0; kk < 4; ++kk) af[kk] = *(const half8*)(abase + kk * 64);
  }

  unsigned int top5[4][5];
#pragma unroll
  for (int r = 0; r < 4; ++r)
#pragma unroll
    for (int s5 = 0; s5 < 5; ++s5) top5[r][s5] = 0u;

#pragma unroll
  for (int ch = 0; ch < 4; ++ch) {
    __syncthreads();
#pragma unroll
    for (int i = 0; i < 8; ++i) {
      int L = i * 4096 + t * 16;
      int nl = L >> 8, x = L & 255;
      const unsigned char* gs = (const unsigned char*)centC +
          (size_t)(ch * 128 + nl) * 256 + (x ^ ((nl & 7) << 4));
      gload_lds16(smC + i * 4096 + w * 1024, gs);
    }
    __syncthreads();

    f32x4 acc[8];
#pragma unroll
    for (int i = 0; i < 8; ++i) acc[i] = f32x4{0.f, 0.f, 0.f, 0.f};
#pragma unroll
    for (int nfc = 0; nfc < 8; ++nfc) {
      int nl = nfc * 16 + c;
      const unsigned char* bbase = smC + nl * 256;
      int swz = (nl & 7) << 4;
#pragma unroll
      for (int kk = 0; kk < 4; ++kk) {
        half8 bf = *(const half8*)(bbase + ((kk * 64 + g * 16) ^ swz));
        acc[nfc] = mfma16(af[kk], bf, acc[nfc]);
      }
    }

#pragma unroll
    for (int nfc = 0; nfc < 8; ++nfc) {
      int col = ch * 128 + nfc * 16 + c;
      float cnv = c_n[col];
#pragma unroll
      for (int r = 0; r < 4; ++r) {
        float denom = fmaxf(en[r] * cnv, 1e-8f);
        float v = acc[nfc][r] * __builtin_amdgcn_rcpf(denom);
        unsigned int u = __float_as_uint(v);
        u = (u & 0x80000000u) ? ~u : (u | 0x80000000u);
        unsigned int k = (col < 500) ? ((u & 0xFFFFFE00u) | (unsigned)col) : 0u;
        unsigned int t0 = top5[r][0], t1 = top5[r][1], t2 = top5[r][2],
                     t3 = top5[r][3], t4 = top5[r][4];
        top5[r][0] = (k > t0) ? k : t0;
        top5[r][1] = (k > t0) ? t0 : ((k > t1) ? k : t1);
        top5[r][2] = (k > t1) ? t1 : ((k > t2) ? k : t2);
        top5[r][3] = (k > t2) ? t2 : ((k > t3) ? k : t3);
        top5[r][4] = (k > t3) ? t3 : ((k > t4) ? k : t4);
      }
    }
  }

#pragma unroll
  for (int r = 0; r < 4; ++r) {
    int rowA = row0 + w * 16 + g * 4 + r;
    unsigned int h0 = top5[r][0], h1 = top5[r][1], h2 = top5[r][2],
                 h3 = top5[r][3], h4 = top5[r][4];
#pragma unroll
    for (int it5 = 0; it5 < 5; ++it5) {
      unsigned int best = h0;
#pragma unroll
      for (int s = 1; s < 16; s <<= 1) {
        unsigned int o = __shfl_xor(best, s);
        best = (o > best) ? o : best;
      }
      if (c == 0) {
        unsigned int m = best & 0xFFFFFE00u;
        unsigned int uu = (m & 0x80000000u) ? (m ^ 0x80000000u) : ~m;
        out[(size_t)rowA * 6 + it5] = __uint_as_float(uu);
      }
      bool pop = (h0 == best);
      h0 = pop ? h1 : h0;
      h1 = pop ? h2 : h1;
      h2 = pop ? h3 : h2;
      h3 = pop ? h4 : h3;
      h4 = pop ? 0u : h4;
    }
  }
}

// ---------------------------------------------------------------------------
extern "C" void kernel_launch(void* const* d_in, const int* in_sizes, int n_in,
                              void* d_out, int out_size, void* d_ws, size_t ws_size,
                              hipStream_t stream) {
  (void)in_sizes; (void)n_in; (void)out_size; (void)ws_size;
  const float* cue      = (const float*)d_in[0];
  const float* internal = (const float*)d_in[1];
  const float* reward   = (const float*)d_in[2];
  const float* tsp      = (const float*)d_in[3];
  const float* emo      = (const float*)d_in[4];
  const float* cent     = (const float*)d_in[5];
  const float* enc_w1   = (const float*)d_in[6];
  const float* enc_b1   = (const float*)d_in[7];
  const float* enc_w2   = (const float*)d_in[8];
  const float* enc_b2   = (const float*)d_in[9];
  const float* imp_w1   = (const float*)d_in[10];
  const float* imp_b1   = (const float*)d_in[11];
  const float* imp_w2   = (const float*)d_in[12];
  const float* imp_b2   = (const float*)d_in[13];
  float* out = (float*)d_out;

  unsigned char* ws = (unsigned char*)d_ws;
  unsigned short* h1     = (unsigned short*)(ws + 0);         // 16777216
  unsigned short* enc    = (unsigned short*)(ws + 16777216);  //  8388608
  unsigned short* W1T    = (unsigned short*)(ws + 25165824);  //   393216
  unsigned short* W2T    = (unsigned short*)(ws + 25559040);  //    65536
  unsigned short* impW1T = (unsigned short*)(ws + 25624576);  //   122880
  unsigned short* centC  = (unsigned short*)(ws + 25747456);  //   131072
  float*          c_n    = (float*)(ws + 25878528);           //     2048
  unsigned short* tail   = (unsigned short*)(ws + 25880576);  //   524288

  k_prep<<<768, 256, 0, stream>>>(enc_w1, enc_w2, imp_w1, cent, reward, tsp, emo,
                                  W1T, W2T, impW1T, centC, c_n, tail);
  k_encimp<<<512, 512, 0, stream>>>(cue, internal, emo, W1T, impW1T, tail,
                                    enc_b1, imp_b1, imp_w2, imp_b2, h1, out);
  k_enc2<<<dim3(256, 2), 256, 0, stream>>>(h1, W2T, enc_b2, enc);
  k_sims<<<512, 256, 0, stream>>>(enc, centC, c_n, out);
}